// Round 1
// baseline (280.145 us; speedup 1.0000x reference)
//
#include <hip/hip_runtime.h>
#include <hip/hip_bf16.h>

typedef short short8 __attribute__((ext_vector_type(8)));
typedef float f32x4 __attribute__((ext_vector_type(4)));

#define S_IMG 16384
#define N_TXT 8192
#define DIM   512

__device__ inline unsigned short f2bf(float x) {
  unsigned u = __builtin_bit_cast(unsigned, x);
  unsigned r = (u + 0x7FFFu + ((u >> 16) & 1u)) >> 16;  // RNE
  return (unsigned short)r;
}

__device__ inline double wave_reduce_add_d(double v) {
#pragma unroll
  for (int m = 32; m; m >>= 1) v += __shfl_xor(v, m, 64);
  return v;
}

// ---------------- kernel 1: normalize txt rows -> ztxt f32 (d_out) + bf16 (ws) -------------
__global__ __launch_bounds__(256) void k_norm_txt(const float* __restrict__ txt,
                                                  float* __restrict__ ztxt_f32,
                                                  unsigned short* __restrict__ Bbf) {
  int row  = blockIdx.x * 4 + (threadIdx.x >> 6);
  int lane = threadIdx.x & 63;
  const float* src = txt + (size_t)row * DIM;
  float4 v0 = reinterpret_cast<const float4*>(src)[lane];
  float4 v1 = reinterpret_cast<const float4*>(src)[lane + 64];
  double ss = (double)v0.x * v0.x + (double)v0.y * v0.y + (double)v0.z * v0.z + (double)v0.w * v0.w
            + (double)v1.x * v1.x + (double)v1.y * v1.y + (double)v1.z * v1.z + (double)v1.w * v1.w;
  ss = wave_reduce_add_d(ss);
  float sc = (float)(1.0 / (sqrt(ss) + 1e-12));
  float o[8] = {v0.x * sc, v0.y * sc, v0.z * sc, v0.w * sc,
                v1.x * sc, v1.y * sc, v1.z * sc, v1.w * sc};
  float* dst = ztxt_f32 + (size_t)row * DIM;   // base is odd-float offset -> scalar stores
#pragma unroll
  for (int j = 0; j < 4; ++j) dst[4 * lane + j] = o[j];
#pragma unroll
  for (int j = 0; j < 4; ++j) dst[256 + 4 * lane + j] = o[4 + j];
  ushort4 p0 = make_ushort4(f2bf(o[0]), f2bf(o[1]), f2bf(o[2]), f2bf(o[3]));
  ushort4 p1 = make_ushort4(f2bf(o[4]), f2bf(o[5]), f2bf(o[6]), f2bf(o[7]));
  reinterpret_cast<ushort4*>(Bbf + (size_t)row * DIM)[lane]       = p0;
  reinterpret_cast<ushort4*>(Bbf + (size_t)row * DIM + 256)[lane] = p1;
}

// ---------------- kernel 2: per-image tp-loss + segmented packed atomicMin ------------------
__global__ __launch_bounds__(256) void k_img_loss(const float* __restrict__ img,
                                                  const float* __restrict__ ztxt_f32,
                                                  const int* __restrict__ key_idx,
                                                  const float* __restrict__ tp,
                                                  const float* __restrict__ bp,
                                                  unsigned long long* __restrict__ seg,
                                                  float* __restrict__ invnorm) {
  int row  = blockIdx.x * 4 + (threadIdx.x >> 6);
  int lane = threadIdx.x & 63;
  const float* src = img + (size_t)row * DIM;
  float4 a0 = reinterpret_cast<const float4*>(src)[lane];
  float4 a1 = reinterpret_cast<const float4*>(src)[lane + 64];
  int key = key_idx[row];
  const float* zt = ztxt_f32 + (size_t)key * DIM;  // unaligned base -> scalar loads
  float z0[4], z1[4];
#pragma unroll
  for (int j = 0; j < 4; ++j) z0[j] = zt[4 * lane + j];
#pragma unroll
  for (int j = 0; j < 4; ++j) z1[j] = zt[256 + 4 * lane + j];
  double ss = (double)a0.x * a0.x + (double)a0.y * a0.y + (double)a0.z * a0.z + (double)a0.w * a0.w
            + (double)a1.x * a1.x + (double)a1.y * a1.y + (double)a1.z * a1.z + (double)a1.w * a1.w;
  double dp = (double)a0.x * z0[0] + (double)a0.y * z0[1] + (double)a0.z * z0[2] + (double)a0.w * z0[3]
            + (double)a1.x * z1[0] + (double)a1.y * z1[1] + (double)a1.z * z1[2] + (double)a1.w * z1[3];
  ss = wave_reduce_add_d(ss);
  dp = wave_reduce_add_d(dp);
  if (lane == 0) {
    double inv = 1.0 / (sqrt(ss) + 1e-12);
    invnorm[row] = (float)inv;
    float t = expf(tp[0]);
    float logit = (float)(dp * inv) * t + bp[0];
    float loss = log1pf(expf(-logit));  // softplus(-logit); logit in [-20.1, 0.1]
    unsigned long long pk =
        ((unsigned long long)__builtin_bit_cast(unsigned, loss) << 32) | (unsigned)row;
    atomicMin(seg + key, pk);
  }
}

// ---------------- kernel 3: select winner per key, gather + normalize ----------------------
__global__ __launch_bounds__(256) void k_select(const float* __restrict__ img,
                                                const unsigned long long* __restrict__ seg,
                                                const float* __restrict__ invnorm,
                                                float* __restrict__ zsel_f32,
                                                float* __restrict__ idx_out,
                                                unsigned short* __restrict__ Abf) {
  int k    = blockIdx.x * 4 + (threadIdx.x >> 6);
  int lane = threadIdx.x & 63;
  unsigned long long pk = seg[k];
  float* dst = zsel_f32 + (size_t)k * DIM;
  float o[8];
  if (pk == 0xFFFFFFFFFFFFFFFFull) {
#pragma unroll
    for (int j = 0; j < 8; ++j) o[j] = 0.0f;
    if (lane == 0) idx_out[k] = -1.0f;
  } else {
    int sel = (int)(pk & 0xFFFFFFFFull);
    float invf = invnorm[sel];
    const float* src = img + (size_t)sel * DIM;
    float4 v0 = reinterpret_cast<const float4*>(src)[lane];
    float4 v1 = reinterpret_cast<const float4*>(src)[lane + 64];
    o[0] = v0.x * invf; o[1] = v0.y * invf; o[2] = v0.z * invf; o[3] = v0.w * invf;
    o[4] = v1.x * invf; o[5] = v1.y * invf; o[6] = v1.z * invf; o[7] = v1.w * invf;
    if (lane == 0) idx_out[k] = (float)sel;
  }
#pragma unroll
  for (int j = 0; j < 4; ++j) dst[4 * lane + j] = o[j];
#pragma unroll
  for (int j = 0; j < 4; ++j) dst[256 + 4 * lane + j] = o[4 + j];
  ushort4 p0 = make_ushort4(f2bf(o[0]), f2bf(o[1]), f2bf(o[2]), f2bf(o[3]));
  ushort4 p1 = make_ushort4(f2bf(o[4]), f2bf(o[5]), f2bf(o[6]), f2bf(o[7]));
  reinterpret_cast<ushort4*>(Abf + (size_t)k * DIM)[lane]       = p0;
  reinterpret_cast<ushort4*>(Abf + (size_t)k * DIM + 256)[lane] = p1;
}

// ---------------- kernel 4: Zsel @ Ztxt^T * t + b  -> logits, fused loss -------------------
#define BM 128
#define BN 128
#define BK 32
#define LDK 40  // +8 bf16 pad: 80B row stride -> <=2-way LDS bank aliasing (free)

__global__ __launch_bounds__(256) void k_gemm(const unsigned short* __restrict__ A,
                                              const unsigned short* __restrict__ B,
                                              float* __restrict__ Cout,
                                              const float* __restrict__ tp,
                                              const float* __restrict__ bp,
                                              double* __restrict__ loss_acc) {
  __shared__ __align__(16) unsigned short lA[BM * LDK];
  __shared__ __align__(16) unsigned short lB[BM * LDK];
  int tid = threadIdx.x, lane = tid & 63, w = tid >> 6;
  int wm = w >> 1, wn = w & 1;
  int bm = blockIdx.x * BM, bn = blockIdx.y * BN;
  f32x4 acc[4][4] = {};
  int fr = lane & 15;         // row within 16x16 frag
  int fk = (lane >> 4) * 8;   // k-chunk

  for (int kt = 0; kt < DIM; kt += BK) {
#pragma unroll
    for (int s = 0; s < 2; ++s) {
      int id = tid + s * 256;             // 0..511 : 128 rows x 4 chunks
      int r = id >> 2, c = (id & 3) * 8;
      *reinterpret_cast<short8*>(&lA[r * LDK + c]) =
          *reinterpret_cast<const short8*>(A + ((size_t)(bm + r)) * DIM + kt + c);
      *reinterpret_cast<short8*>(&lB[r * LDK + c]) =
          *reinterpret_cast<const short8*>(B + ((size_t)(bn + r)) * DIM + kt + c);
    }
    __syncthreads();
    short8 af[4], bfr[4];
#pragma unroll
    for (int m = 0; m < 4; ++m)
      af[m] = *reinterpret_cast<const short8*>(&lA[(wm * 64 + m * 16 + fr) * LDK + fk]);
#pragma unroll
    for (int n = 0; n < 4; ++n)
      bfr[n] = *reinterpret_cast<const short8*>(&lB[(wn * 64 + n * 16 + fr) * LDK + fk]);
#pragma unroll
    for (int m = 0; m < 4; ++m)
#pragma unroll
      for (int n = 0; n < 4; ++n)
        acc[m][n] = __builtin_amdgcn_mfma_f32_16x16x32_bf16(af[m], bfr[n], acc[m][n], 0, 0, 0);
    __syncthreads();
  }

  // epilogue: logits write + fused loss
  float t = expf(tp[0]), bb = bp[0];
  float local = 0.f;
  int cr = (lane >> 4) * 4;  // C row base (m89-verified mapping)
  int cc = lane & 15;        // C col
#pragma unroll
  for (int m = 0; m < 4; ++m) {
#pragma unroll
    for (int n = 0; n < 4; ++n) {
      int col = bn + wn * 64 + n * 16 + cc;
#pragma unroll
      for (int r = 0; r < 4; ++r) {
        int row = bm + wm * 64 + m * 16 + cr + r;
        float logit = acc[m][n][r] * t + bb;
        Cout[(size_t)row * N_TXT + col] = logit;
        float x = (row == col) ? -logit : logit;   // -(label*logit)
        local += log1pf(expf(x));
      }
    }
  }
#pragma unroll
  for (int m = 32; m; m >>= 1) local += __shfl_xor(local, m, 64);
  __shared__ float wsum[4];
  if (lane == 0) wsum[w] = local;
  __syncthreads();
  if (tid == 0) atomicAdd(loss_acc, (double)(wsum[0] + wsum[1] + wsum[2] + wsum[3]));
}

// ---------------- kernel 5: finalize loss ---------------------------------------------------
__global__ void k_final(const double* __restrict__ loss_acc, float* __restrict__ out0) {
  out0[0] = (float)(loss_acc[0] / (double)N_TXT);
}

extern "C" void kernel_launch(void* const* d_in, const int* in_sizes, int n_in,
                              void* d_out, int out_size, void* d_ws, size_t ws_size,
                              hipStream_t stream) {
  const float* img = (const float*)d_in[0];
  const float* txt = (const float*)d_in[1];
  const int* key   = (const int*)d_in[2];
  const float* tp  = (const float*)d_in[3];
  const float* bp  = (const float*)d_in[4];

  float* out        = (float*)d_out;
  float* out_loss   = out;                                   // [1]
  float* out_zsel   = out + 1;                               // [8192*512]
  float* out_ztxt   = out_zsel + (size_t)N_TXT * DIM;        // [8192*512]
  float* out_logits = out_ztxt + (size_t)N_TXT * DIM;        // [8192*8192]
  float* out_idx    = out_logits + (size_t)N_TXT * N_TXT;    // [8192]

  char* w = (char*)d_ws;
  unsigned long long* seg = (unsigned long long*)w;          // 64 KiB
  double* loss_acc = (double*)(w + 65536);                   // 8 B (+pad)
  float* invnorm   = (float*)(w + 65792);                    // 64 KiB
  unsigned short* Abf = (unsigned short*)(w + 65792 + 65536);        // 8 MiB, 16B aligned
  unsigned short* Bbf = Abf + (size_t)N_TXT * DIM;                   // 8 MiB
  size_t need = 65792 + 65536 + 2ull * N_TXT * DIM * sizeof(unsigned short);
  if (ws_size < need) return;

  hipMemsetAsync(seg, 0xFF, (size_t)N_TXT * sizeof(unsigned long long), stream);
  hipMemsetAsync(loss_acc, 0, sizeof(double), stream);

  k_norm_txt<<<N_TXT / 4, 256, 0, stream>>>(txt, out_ztxt, Bbf);
  k_img_loss<<<S_IMG / 4, 256, 0, stream>>>(img, out_ztxt, key, tp, bp, seg, invnorm);
  k_select<<<N_TXT / 4, 256, 0, stream>>>(img, seg, invnorm, out_zsel, out_idx, Abf);
  k_gemm<<<dim3(N_TXT / BM, N_TXT / BN), 256, 0, stream>>>(Abf, Bbf, out_logits, tp, bp, loss_acc);
  k_final<<<1, 1, 0, stream>>>(loss_acc, out_loss);
}

// Round 2
// 175.533 us; speedup vs baseline: 1.5960x; 1.5960x over previous
//
#include <hip/hip_runtime.h>
#include <hip/hip_bf16.h>

typedef short short8 __attribute__((ext_vector_type(8)));
typedef float f32x4 __attribute__((ext_vector_type(4)));

#define S_IMG 16384
#define N_TXT 8192
#define DIM   512

#if __has_builtin(__builtin_amdgcn_exp2f)
#define FAST_EXP2(x) __builtin_amdgcn_exp2f(x)
#else
#define FAST_EXP2(x) exp2f(x)
#endif
#if __has_builtin(__builtin_amdgcn_logf)
#define FAST_LOG2(x) __builtin_amdgcn_logf(x)   // v_log_f32 = log2
#else
#define FAST_LOG2(x) log2f(x)
#endif

// softplus(x) = max(x,0) + ln2 * log2(1 + exp2(-|x|*log2e))
__device__ inline float softplus_f(float x) {
  float e = FAST_EXP2(-fabsf(x) * 1.44269504088896f);
  return fmaxf(x, 0.f) + 0.69314718055995f * FAST_LOG2(1.0f + e);
}

#define GLOAD16(g, l)                                                   \
  __builtin_amdgcn_global_load_lds(                                     \
      (const __attribute__((address_space(1))) void*)(g),               \
      (__attribute__((address_space(3))) void*)(l), 16, 0, 0)

__device__ inline unsigned short f2bf(float x) {
  unsigned u = __builtin_bit_cast(unsigned, x);
  unsigned r = (u + 0x7FFFu + ((u >> 16) & 1u)) >> 16;  // RNE
  return (unsigned short)r;
}

__device__ inline double wave_reduce_add_d(double v) {
#pragma unroll
  for (int m = 32; m; m >>= 1) v += __shfl_xor(v, m, 64);
  return v;
}

// ---------------- kernel 1: normalize txt rows -> ztxt f32 (d_out) + bf16 (ws) -------------
__global__ __launch_bounds__(256) void k_norm_txt(const float* __restrict__ txt,
                                                  float* __restrict__ ztxt_f32,
                                                  unsigned short* __restrict__ Bbf) {
  int row  = blockIdx.x * 4 + (threadIdx.x >> 6);
  int lane = threadIdx.x & 63;
  const float* src = txt + (size_t)row * DIM;
  float4 v0 = reinterpret_cast<const float4*>(src)[lane];
  float4 v1 = reinterpret_cast<const float4*>(src)[lane + 64];
  double ss = (double)v0.x * v0.x + (double)v0.y * v0.y + (double)v0.z * v0.z + (double)v0.w * v0.w
            + (double)v1.x * v1.x + (double)v1.y * v1.y + (double)v1.z * v1.z + (double)v1.w * v1.w;
  ss = wave_reduce_add_d(ss);
  float sc = (float)(1.0 / (sqrt(ss) + 1e-12));
  float o[8] = {v0.x * sc, v0.y * sc, v0.z * sc, v0.w * sc,
                v1.x * sc, v1.y * sc, v1.z * sc, v1.w * sc};
  float* dst = ztxt_f32 + (size_t)row * DIM;   // base is odd-float offset -> scalar stores
#pragma unroll
  for (int j = 0; j < 4; ++j) dst[4 * lane + j] = o[j];
#pragma unroll
  for (int j = 0; j < 4; ++j) dst[256 + 4 * lane + j] = o[4 + j];
  ushort4 p0 = make_ushort4(f2bf(o[0]), f2bf(o[1]), f2bf(o[2]), f2bf(o[3]));
  ushort4 p1 = make_ushort4(f2bf(o[4]), f2bf(o[5]), f2bf(o[6]), f2bf(o[7]));
  reinterpret_cast<ushort4*>(Bbf + (size_t)row * DIM)[lane]       = p0;
  reinterpret_cast<ushort4*>(Bbf + (size_t)row * DIM + 256)[lane] = p1;
}

// ---------------- kernel 2: per-image tp-loss + segmented packed atomicMin ------------------
__global__ __launch_bounds__(256) void k_img_loss(const float* __restrict__ img,
                                                  const float* __restrict__ ztxt_f32,
                                                  const int* __restrict__ key_idx,
                                                  const float* __restrict__ tp,
                                                  const float* __restrict__ bp,
                                                  unsigned long long* __restrict__ seg,
                                                  float* __restrict__ invnorm) {
  int row  = blockIdx.x * 4 + (threadIdx.x >> 6);
  int lane = threadIdx.x & 63;
  const float* src = img + (size_t)row * DIM;
  float4 a0 = reinterpret_cast<const float4*>(src)[lane];
  float4 a1 = reinterpret_cast<const float4*>(src)[lane + 64];
  int key = key_idx[row];
  const float* zt = ztxt_f32 + (size_t)key * DIM;  // unaligned base -> scalar loads
  float z0[4], z1[4];
#pragma unroll
  for (int j = 0; j < 4; ++j) z0[j] = zt[4 * lane + j];
#pragma unroll
  for (int j = 0; j < 4; ++j) z1[j] = zt[256 + 4 * lane + j];
  double ss = (double)a0.x * a0.x + (double)a0.y * a0.y + (double)a0.z * a0.z + (double)a0.w * a0.w
            + (double)a1.x * a1.x + (double)a1.y * a1.y + (double)a1.z * a1.z + (double)a1.w * a1.w;
  double dp = (double)a0.x * z0[0] + (double)a0.y * z0[1] + (double)a0.z * z0[2] + (double)a0.w * z0[3]
            + (double)a1.x * z1[0] + (double)a1.y * z1[1] + (double)a1.z * z1[2] + (double)a1.w * z1[3];
  ss = wave_reduce_add_d(ss);
  dp = wave_reduce_add_d(dp);
  if (lane == 0) {
    double inv = 1.0 / (sqrt(ss) + 1e-12);
    invnorm[row] = (float)inv;
    float t = expf(tp[0]);
    float logit = (float)(dp * inv) * t + bp[0];
    float loss = log1pf(expf(-logit));  // softplus(-logit); exact libm here (argmin-critical)
    unsigned long long pk =
        ((unsigned long long)__builtin_bit_cast(unsigned, loss) << 32) | (unsigned)row;
    atomicMin(seg + key, pk);
  }
}

// ---------------- kernel 3: select winner per key, gather + normalize ----------------------
__global__ __launch_bounds__(256) void k_select(const float* __restrict__ img,
                                                const unsigned long long* __restrict__ seg,
                                                const float* __restrict__ invnorm,
                                                float* __restrict__ zsel_f32,
                                                float* __restrict__ idx_out,
                                                unsigned short* __restrict__ Abf) {
  int k    = blockIdx.x * 4 + (threadIdx.x >> 6);
  int lane = threadIdx.x & 63;
  unsigned long long pk = seg[k];
  float* dst = zsel_f32 + (size_t)k * DIM;
  float o[8];
  if (pk == 0xFFFFFFFFFFFFFFFFull) {
#pragma unroll
    for (int j = 0; j < 8; ++j) o[j] = 0.0f;
    if (lane == 0) idx_out[k] = -1.0f;
  } else {
    int sel = (int)(pk & 0xFFFFFFFFull);
    float invf = invnorm[sel];
    const float* src = img + (size_t)sel * DIM;
    float4 v0 = reinterpret_cast<const float4*>(src)[lane];
    float4 v1 = reinterpret_cast<const float4*>(src)[lane + 64];
    o[0] = v0.x * invf; o[1] = v0.y * invf; o[2] = v0.z * invf; o[3] = v0.w * invf;
    o[4] = v1.x * invf; o[5] = v1.y * invf; o[6] = v1.z * invf; o[7] = v1.w * invf;
    if (lane == 0) idx_out[k] = (float)sel;
  }
#pragma unroll
  for (int j = 0; j < 4; ++j) dst[4 * lane + j] = o[j];
#pragma unroll
  for (int j = 0; j < 4; ++j) dst[256 + 4 * lane + j] = o[4 + j];
  ushort4 p0 = make_ushort4(f2bf(o[0]), f2bf(o[1]), f2bf(o[2]), f2bf(o[3]));
  ushort4 p1 = make_ushort4(f2bf(o[4]), f2bf(o[5]), f2bf(o[6]), f2bf(o[7]));
  reinterpret_cast<ushort4*>(Abf + (size_t)k * DIM)[lane]       = p0;
  reinterpret_cast<ushort4*>(Abf + (size_t)k * DIM + 256)[lane] = p1;
}

// ---------------- kernel 4: Zsel @ Ztxt^T * t + b  -> logits, fused loss -------------------
// m97 structure: 128x128 tile, BK=32, linear LDS, global_load_lds width=16,
// 2-barrier K-loop, 4 waves x (4x4 of 16x16x32 bf16 MFMA).
#define BM 128
#define BN 128
#define BK 32

__global__ __launch_bounds__(256) void k_gemm(const unsigned short* __restrict__ A,
                                              const unsigned short* __restrict__ B,
                                              float* __restrict__ Cout,
                                              const float* __restrict__ tp,
                                              const float* __restrict__ bp,
                                              float* __restrict__ part) {
  __shared__ __align__(16) unsigned short lA[BM * BK];  // linear [128][32]
  __shared__ __align__(16) unsigned short lB[BM * BK];
  int tid = threadIdx.x, lane = tid & 63, w = tid >> 6;
  int wm = w >> 1, wn = w & 1;
  int bm = blockIdx.x * BM, bn = blockIdx.y * BN;
  f32x4 acc[4][4] = {};
  int fr = lane & 15;         // row within 16x16 frag
  int fk = (lane >> 4) * 8;   // k-chunk (elements)

  // wave w stages 1KB chunks q=2w, 2w+1 of each tile (chunk q = rows q*16..q*16+15)
  int q0 = 2 * w;
  int srow = q0 * 16 + (lane >> 2);         // per-lane source row within tile
  int scol = (lane & 3) * 8;                // per-lane source col (elements)
  const unsigned short* gA = A + (size_t)(bm + srow) * DIM + scol;
  const unsigned short* gB = B + (size_t)(bn + srow) * DIM + scol;

  for (int kt = 0; kt < DIM; kt += BK) {
    GLOAD16(gA,            &lA[q0 * 512]);
    GLOAD16(gA + 16 * DIM, &lA[q0 * 512 + 512]);
    GLOAD16(gB,            &lB[q0 * 512]);
    GLOAD16(gB + 16 * DIM, &lB[q0 * 512 + 512]);
    gA += BK; gB += BK;
    __syncthreads();   // compiler drains vmcnt(0) before s_barrier

    short8 af[4], bfr[4];
#pragma unroll
    for (int m = 0; m < 4; ++m)
      af[m] = *reinterpret_cast<const short8*>(&lA[(wm * 64 + m * 16 + fr) * BK + fk]);
#pragma unroll
    for (int n = 0; n < 4; ++n)
      bfr[n] = *reinterpret_cast<const short8*>(&lB[(wn * 64 + n * 16 + fr) * BK + fk]);
#pragma unroll
    for (int m = 0; m < 4; ++m)
#pragma unroll
      for (int n = 0; n < 4; ++n)
        acc[m][n] = __builtin_amdgcn_mfma_f32_16x16x32_bf16(af[m], bfr[n], acc[m][n], 0, 0, 0);
    __syncthreads();
  }

  // epilogue: logits write + fused loss (fast exp2/log2 softplus)
  float t = expf(tp[0]), bb = bp[0];
  float local = 0.f;
  int cr = (lane >> 4) * 4;  // C row base (m89-verified mapping)
  int cc = lane & 15;        // C col
#pragma unroll
  for (int m = 0; m < 4; ++m) {
#pragma unroll
    for (int n = 0; n < 4; ++n) {
      int col = bn + wn * 64 + n * 16 + cc;
#pragma unroll
      for (int r = 0; r < 4; ++r) {
        int row = bm + wm * 64 + m * 16 + cr + r;
        float logit = acc[m][n][r] * t + bb;
        Cout[(size_t)row * N_TXT + col] = logit;
        float x = (row == col) ? -logit : logit;   // -(label*logit)
        local += softplus_f(x);
      }
    }
  }
#pragma unroll
  for (int m = 32; m; m >>= 1) local += __shfl_xor(local, m, 64);
  __shared__ float wsum[4];
  if (lane == 0) wsum[w] = local;
  __syncthreads();
  if (tid == 0) {
    int bid = blockIdx.y * gridDim.x + blockIdx.x;
    part[bid] = wsum[0] + wsum[1] + wsum[2] + wsum[3];
  }
}

// ---------------- kernel 5: reduce partials, finalize loss ---------------------------------
#define NPART 4096
__global__ __launch_bounds__(256) void k_final(const float* __restrict__ part,
                                               float* __restrict__ out0) {
  double s = 0.0;
  for (int i = threadIdx.x; i < NPART; i += 256) s += (double)part[i];
  s = wave_reduce_add_d(s);
  __shared__ double ws[4];
  if ((threadIdx.x & 63) == 0) ws[threadIdx.x >> 6] = s;
  __syncthreads();
  if (threadIdx.x == 0)
    out0[0] = (float)((ws[0] + ws[1] + ws[2] + ws[3]) / (double)N_TXT);
}

extern "C" void kernel_launch(void* const* d_in, const int* in_sizes, int n_in,
                              void* d_out, int out_size, void* d_ws, size_t ws_size,
                              hipStream_t stream) {
  const float* img = (const float*)d_in[0];
  const float* txt = (const float*)d_in[1];
  const int* key   = (const int*)d_in[2];
  const float* tp  = (const float*)d_in[3];
  const float* bp  = (const float*)d_in[4];

  float* out        = (float*)d_out;
  float* out_loss   = out;                                   // [1]
  float* out_zsel   = out + 1;                               // [8192*512]
  float* out_ztxt   = out_zsel + (size_t)N_TXT * DIM;        // [8192*512]
  float* out_logits = out_ztxt + (size_t)N_TXT * DIM;        // [8192*8192]
  float* out_idx    = out_logits + (size_t)N_TXT * N_TXT;    // [8192]

  char* w = (char*)d_ws;
  unsigned long long* seg = (unsigned long long*)w;          // 64 KiB
  float* invnorm   = (float*)(w + 65536);                    // 64 KiB
  float* part      = (float*)(w + 131072);                   // 16 KiB
  unsigned short* Abf = (unsigned short*)(w + 131072 + 16384);      // 8 MiB, 16B aligned
  unsigned short* Bbf = Abf + (size_t)N_TXT * DIM;                  // 8 MiB
  size_t need = 131072 + 16384 + 2ull * N_TXT * DIM * sizeof(unsigned short);
  if (ws_size < need) return;

  hipMemsetAsync(seg, 0xFF, (size_t)N_TXT * sizeof(unsigned long long), stream);

  k_norm_txt<<<N_TXT / 4, 256, 0, stream>>>(txt, out_ztxt, Bbf);
  k_img_loss<<<S_IMG / 4, 256, 0, stream>>>(img, out_ztxt, key, tp, bp, seg, invnorm);
  k_select<<<N_TXT / 4, 256, 0, stream>>>(img, seg, invnorm, out_zsel, out_idx, Abf);
  k_gemm<<<dim3(N_TXT / BM, N_TXT / BN), 256, 0, stream>>>(Abf, Bbf, out_logits, tp, bp, part);
  k_final<<<1, 256, 0, stream>>>(part, out_loss);
}